// Round 1
// 15496.727 us; speedup vs baseline: 1.0119x; 1.0119x over previous
//
#include <hip/hip_runtime.h>
#include <math.h>

#define T_STEPS 16384
#define IN_DIM  14
#define H_DIM   100
#define G_DIM   300   // 3*H

// LDS float offsets inside each 1024-float buffer
#define H1OFF 0      // h1[0..100)
#define H2OFF 128    // h2[0..100)
#define AOFF  256    // a (layer-1 input preacts) [0..300)

typedef float f2 __attribute__((ext_vector_type(2)));

#define REP25(M) M(0) M(1) M(2) M(3) M(4) M(5) M(6) M(7) M(8) M(9) M(10) M(11) \
                 M(12) M(13) M(14) M(15) M(16) M(17) M(18) M(19) M(20) M(21) M(22) M(23) M(24)

// ---------------- Phase 0: gi0[t][j] = b_ih0[j] + sum_k x[t][k]*w_ih0[j][k] ----------------
__global__ void gi0_kernel(const float* __restrict__ x,
                           const float* __restrict__ w_ih0,
                           const float* __restrict__ b_ih0,
                           float* __restrict__ gi0) {
    int e = blockIdx.x * blockDim.x + threadIdx.x;
    if (e >= T_STEPS * G_DIM) return;
    int t = e / G_DIM;
    int j = e - t * G_DIM;
    const float* xr = x + t * IN_DIM;
    const float* wr = w_ih0 + j * IN_DIM;
    float acc = b_ih0[j];
    #pragma unroll
    for (int k = 0; k < IN_DIM; ++k) acc = fmaf(xr[k], wr[k], acc);
    gi0[e] = acc;
}

// ---------------- Phase 1: persistent single-workgroup sequential GRU ----------------
// RESTRUCTURED (this round): one barrier per timestep, gates fused into the
// dot-product threads.
//   waves 0-4 ("gate waves"): lanes 0-39 = A-lanes (one gate each: own FULL
//     r-row and z-row, 200 f32 in named f2 SSA regs). lanes 40-59 = B-lanes
//     (own the n-rows of two adjacent gates). lanes 60-63 idle (clone lane 59).
//     Gates 0..99 -> layer-0 (w_hh0 vs h1), gates 100..199 -> layer-1 rec
//     (w_hh1 vs h2). B->A n-preact handoff via 2x ds_bpermute (in-wave, no
//     barrier); A-lane then does sigmoid/sigmoid/tanh and writes h_new.
//   waves 5-7: layer-1 input projection, 150 active lanes x 2 rows of w_ih1,
//     writing float2 preacts into the double-buffered "a" slab, consumed by
//     layer-1 gate lanes next iteration (l1 lags l0 by 2 steps).
// h1/h2/a are double-buffered (bufA/bufB) -> ONE __syncthreads per iteration.
// All per-row accumulation patterns + gate formulas are bit-identical to the
// previous kernel (absmax 0.0 preserved). Weight rows stay as 100 named f2
// values per lane -- float arrays would go to scratch (SROA before unroll).
__global__ __launch_bounds__(512, 2)
void gru_seq_kernel(const float* __restrict__ gi0,
                    const float* __restrict__ w_hh0,
                    const float* __restrict__ b_hh0,
                    const float* __restrict__ w_ih1,
                    const float* __restrict__ b_ih1,
                    const float* __restrict__ w_hh1,
                    const float* __restrict__ b_hh1,
                    const float* __restrict__ fc_w,
                    const float* __restrict__ fc_b,
                    float* __restrict__ out) {
    __shared__ __align__(16) float bufA[1024];
    __shared__ __align__(16) float bufB[1024];

    const int tid = threadIdx.x;
    const int wv = tid >> 6;
    const int ln = tid & 63;
    const bool gateWave = (tid < 320);

    const float* pra; const float* prb; float bias0, bias1;
    int hbase4 = 0;      // float4 index of this lane's h vector (0 = h1, 32 = h2)
    bool isA = false;
    int gg = 0;          // global gate id for A-lanes (0..199)
    int jw = 0;          // write index (gate-local j, or l1in float2 slot)

    if (gateWave) {
        if (ln < 40) {                       // A-lane: r-row + z-row of gate gg
            isA = true;
            gg = wv * 40 + ln;
            int gl = (gg < 100) ? gg : gg - 100;
            const float* wm = (gg < 100) ? w_hh0 : w_hh1;
            const float* bm = (gg < 100) ? b_hh0 : b_hh1;
            pra = wm + (size_t)gl * H_DIM;            // r-row
            prb = wm + (size_t)(gl + 100) * H_DIM;    // z-row
            bias0 = bm[gl]; bias1 = bm[gl + 100];
            hbase4 = (gg < 100) ? (H1OFF / 4) : (H2OFF / 4);
            jw = gl;
        } else {                             // B-lane: n-rows of gates (pb, pb+1)
            int b = (ln < 60) ? (ln - 40) : 19;       // lanes 60-63 clone lane 59
            int pb = wv * 40 + 2 * b;
            int gl = (pb < 100) ? pb : pb - 100;
            const float* wm = (pb < 100) ? w_hh0 : w_hh1;
            const float* bm = (pb < 100) ? b_hh0 : b_hh1;
            pra = wm + (size_t)(200 + gl) * H_DIM;
            prb = wm + (size_t)(201 + gl) * H_DIM;
            bias0 = bm[200 + gl]; bias1 = bm[201 + gl];
            hbase4 = (pb < 100) ? (H1OFF / 4) : (H2OFF / 4);
        }
    } else {                                 // l1in: 2 rows of w_ih1
        int s = tid - 320;
        int q = (s < 150) ? s : 149;                  // tail lanes clone, never write
        pra = w_ih1 + (size_t)(2 * q) * H_DIM;
        prb = w_ih1 + (size_t)(2 * q + 1) * H_DIM;
        bias0 = b_ih1[2 * q]; bias1 = b_ih1[2 * q + 1];
        hbase4 = H1OFF / 4;
        jw = q;
    }
    const bool l1inActive = (!gateWave) && (tid - 320 < 150);
    const int hsoff = hbase4 << 2;           // scalar float offset of this lane's h

    // ---- weight registers: 100 named f2 values (200 f32), guaranteed SSA ----
    #define DECLK(k) f2 w0a_##k, w0b_##k, w1a_##k, w1b_##k;
    REP25(DECLK)
    #undef DECLK
    {
        const float4* p0 = reinterpret_cast<const float4*>(pra);
        const float4* p1 = reinterpret_cast<const float4*>(prb);
        #define LOADK(k) { float4 A = p0[k]; w0a_##k.x = A.x; w0a_##k.y = A.y; w0b_##k.x = A.z; w0b_##k.y = A.w; \
                           float4 B = p1[k]; w1a_##k.x = B.x; w1a_##k.y = B.y; w1b_##k.x = B.z; w1b_##k.y = B.w; }
        REP25(LOADK)
        #undef LOADK
    }

    for (int k = tid; k < 1024; k += 512) { bufA[k] = 0.0f; bufB[k] = 0.0f; }
    __syncthreads();

    // T+2 iterations: l0 produces h1(it) for it<T; l1in produces a(it-1) for
    // 1<=it<=T; l1 gates produce h2(it-2) for it>=2. One barrier per iteration.
    for (int it = 0; it < T_STEPS + 2; ++it) {
        float* bc = (it & 1) ? bufB : bufA;   // read buffer (written last iter)
        float* bn = (it & 1) ? bufA : bufB;   // write buffer

        // Prefetch gate inputs (global gi0 for l0, LDS a-slab for l1) + h_old.
        float gr = 0.f, gz = 0.f, gn = 0.f, hold = 0.f;
        if (isA) {
            if (gg < 100) {
                if (it < T_STEPS) {
                    const float* p = gi0 + (size_t)it * G_DIM + jw;
                    gr = p[0]; gz = p[H_DIM]; gn = p[2 * H_DIM];
                }
            } else {
                gr = bc[AOFF + jw];
                gz = bc[AOFF + 100 + jw];
                gn = bc[AOFF + 200 + jw];
            }
            hold = bc[hsoff + jw];
        }

        // Dot phase: 2 rows x 100, packed-f32 FMAs, broadcast ds_read_b128 of h.
        const float4* hb4 = reinterpret_cast<const float4*>(bc) + hbase4;
        f2 acc0, acc1, acc2, acc3;
        acc0.x = bias0; acc0.y = 0.0f;
        acc1.x = 0.0f;  acc1.y = 0.0f;
        acc2.x = bias1; acc2.y = 0.0f;
        acc3.x = 0.0f;  acc3.y = 0.0f;
        #define DOTK(k) { float4 V = hb4[k]; \
                          f2 va, vb; va.x = V.x; va.y = V.y; vb.x = V.z; vb.y = V.w; \
                          acc0 += w0a_##k * va; acc1 += w0b_##k * vb; \
                          acc2 += w1a_##k * va; acc3 += w1b_##k * vb; }
        REP25(DOTK)
        #undef DOTK
        float d0 = (acc0.x + acc1.x) + (acc0.y + acc1.y);
        float d1 = (acc2.x + acc3.x) + (acc2.y + acc3.y);

        if (gateWave) {
            // B->A handoff of n-row dots: A-lane la pulls from B-lane 40+la/2,
            // parity selects which of B's two gates. Executed by ALL 64 lanes
            // (bpermute sources must be active).
            int src = (40 + (ln >> 1)) << 2;
            float nh0 = __int_as_float(__builtin_amdgcn_ds_bpermute(src, __float_as_int(d0)));
            float nh1 = __int_as_float(__builtin_amdgcn_ds_bpermute(src, __float_as_int(d1)));
            float nh = (ln & 1) ? nh1 : nh0;
            bool act = isA && ((gg < 100) ? (it < T_STEPS) : (it >= 2));
            if (act) {
                float r = 1.0f / (1.0f + expf(-(gr + d0)));
                float z = 1.0f / (1.0f + expf(-(gz + d1)));
                float n = tanhf(gn + r * nh);
                bn[hsoff + jw] = (1.0f - z) * n + z * hold;
            }
        } else if (l1inActive && it >= 1 && it <= T_STEPS) {
            reinterpret_cast<float2*>(bn + AOFF)[jw] = make_float2(d0, d1);
        }
        __syncthreads();
    }

    // FC epilogue: final h2 = h2(T-1) was written at it = T+1 (odd since T is
    // even) -> landed in bufA. out = fc_b + fc_w . h2
    if (tid < 64) {
        float s = 0.0f;
        for (int j = tid; j < H_DIM; j += 64) s = fmaf(fc_w[j], bufA[H2OFF + j], s);
        #pragma unroll
        for (int off = 32; off > 0; off >>= 1) s += __shfl_down(s, off);
        if (tid == 0) out[0] = s + fc_b[0];
    }
}

extern "C" void kernel_launch(void* const* d_in, const int* in_sizes, int n_in,
                              void* d_out, int out_size, void* d_ws, size_t ws_size,
                              hipStream_t stream) {
    const float* x     = (const float*)d_in[0];
    const float* w_ih0 = (const float*)d_in[1];
    const float* w_hh0 = (const float*)d_in[2];
    const float* b_ih0 = (const float*)d_in[3];
    const float* b_hh0 = (const float*)d_in[4];
    const float* w_ih1 = (const float*)d_in[5];
    const float* w_hh1 = (const float*)d_in[6];
    const float* b_ih1 = (const float*)d_in[7];
    const float* b_hh1 = (const float*)d_in[8];
    const float* fc_w  = (const float*)d_in[9];
    const float* fc_b  = (const float*)d_in[10];
    float* out = (float*)d_out;
    float* gi0 = (float*)d_ws;   // T*300 floats = 19.66 MB

    const int total = T_STEPS * G_DIM;
    gi0_kernel<<<(total + 255) / 256, 256, 0, stream>>>(x, w_ih0, b_ih0, gi0);
    gru_seq_kernel<<<1, 512, 0, stream>>>(gi0, w_hh0, b_hh0, w_ih1, b_ih1,
                                          w_hh1, b_hh1, fc_w, fc_b, out);
}